// Round 4
// baseline (1585.827 us; speedup 1.0000x reference)
//
#include <hip/hip_runtime.h>

// ---------------- problem constants ----------------
#define BB 8
#define NQ 300
#define NTQ 50
#define NLAY 6
#define S_TOTAL 20197
#define ROWS (BB*NQ)        // 2400
#define MVAL (BB*S_TOTAL)   // 161576

typedef unsigned short u16;
typedef unsigned int u32;
typedef __bf16 v8bf __attribute__((ext_vector_type(8)));
typedef float f32x4 __attribute__((ext_vector_type(4)));

__device__ __forceinline__ u16 f2b(float f) {
    u32 u = __float_as_uint(f);
    u32 r = (u + 0x7fffu + ((u >> 16) & 1u)) >> 16;
    return (u16)r;
}
__device__ __forceinline__ u32 pk2(float lo, float hi) {
    return (u32)f2b(lo) | ((u32)f2b(hi) << 16);
}

// async global->LDS 16B/lane. LDS dest must be wave-uniform base + lane*16;
// global source address is per-lane (m173: pre-permuted source enables
// arbitrary LDS layouts while keeping the destination linear).
#define ASYNC_CP16(dst_lds, src_g) \
    __builtin_amdgcn_global_load_lds((const __attribute__((address_space(1))) u32*)(src_g), \
                                     (__attribute__((address_space(3))) u32*)(dst_lds), 16, 0, 0)

// ---------------- weight transpose (f32 -> bf16) + bias pack ----------------
// wt layout per layer (element offsets, layer stride 884736):
//   [0) offa_t 384x256 | [98304) wv_t 256x256 | [163840) wout_t 256x256
//   [229376) wl1_t 1024x256 | [491520) wl2_t 256x1024 | [753664) wqk_t 512x256
// bias f32 per layer (stride 2688): boffa[0) bv[384) bout[640) bl1[896) bl2[1920) bqk[2176)
__global__ void transpose_pack(
    const float* Woff, const float* Wa, const float* Wv, const float* Wout,
    const float* Wl1, const float* Wl2, const float* Wq, const float* Wk,
    const float* boff, const float* ba, const float* bvp, const float* bout,
    const float* bl1, const float* bl2, const float* bq, const float* bk,
    u16* wt, float* bias)
{
    int idx = blockIdx.x * 256 + threadIdx.x;
    if (idx < 5308416) {
        int l = idx / 884736;
        int o = idx % 884736;
        float v;
        if (o < 98304) { int n = o >> 8, k = o & 255;
            v = (n < 256) ? Woff[l*65536 + k*256 + n] : Wa[l*32768 + k*128 + (n-256)];
        } else if (o < 163840) { int o2 = o - 98304; int n = o2 >> 8, k = o2 & 255;
            v = Wv[l*65536 + k*256 + n];
        } else if (o < 229376) { int o2 = o - 163840; int n = o2 >> 8, k = o2 & 255;
            v = Wout[l*65536 + k*256 + n];
        } else if (o < 491520) { int o2 = o - 229376; int n = o2 >> 8, k = o2 & 255;
            v = Wl1[l*262144 + k*1024 + n];
        } else if (o < 753664) { int o2 = o - 491520; int n = o2 >> 10, k = o2 & 1023;
            v = Wl2[l*262144 + k*256 + n];
        } else { int o2 = o - 753664; int n = o2 >> 8, k = o2 & 255;
            v = (n < 256) ? Wq[l*65536 + k*256 + n] : Wk[l*65536 + k*256 + (n-256)];
        }
        wt[idx] = f2b(v);
    } else {
        int i2 = idx - 5308416;
        if (i2 < 16128) {
            int l = i2 / 2688, o = i2 % 2688;
            float v;
            if (o < 256)       v = boff[l*256 + o];
            else if (o < 384)  v = ba  [l*128 + (o-256)];
            else if (o < 640)  v = bvp [l*256 + (o-384)];
            else if (o < 896)  v = bout[l*256 + (o-640)];
            else if (o < 1920) v = bl1 [l*1024 + (o-896)];
            else if (o < 2176) v = bl2 [l*256 + (o-1920)];
            else if (o < 2432) v = bq  [l*256 + (o-2176)];
            else               v = bk  [l*256 + (o-2432)];
            bias[i2] = v;
        }
    }
}

// ---------------- src f32 -> bf16 (once; reused by the batched value GEMM) ----
__global__ void src_convert(const float* __restrict__ src, u16* __restrict__ dst)
{
    long i = ((long)blockIdx.x*256 + threadIdx.x)*8;
    float4 a = *(const float4*)(src+i), b4 = *(const float4*)(src+i+4);
    uint4 o = make_uint4(pk2(a.x,a.y), pk2(a.z,a.w), pk2(b4.x,b4.y), pk2(b4.z,b4.w));
    *(uint4*)&dst[i] = o;
}

// ---------------- setup: p_pos, proposals init, layer-0 q, p_ref out, tq pack ----
__global__ void setup_kernel(const float* tgt, const float* refp, float* prop,
                             u16* q_b, float* ppos, u16* tq, float* out_pref)
{
    int row = blockIdx.x, t = threadIdx.x;
    if (row < ROWS) {
        int b = row / NQ, q = row % NQ;
        int k = t >> 6, rem = t & 63, j = rem >> 1;
        float pr = refp[(b*350 + q)*4 + k];
        float dimt = powf(10000.0f, (float)j * (1.0f/32.0f));
        float arg = pr * 6.283185307179586f / dimt;
        float pe = (rem & 1) ? cosf(arg) : sinf(arg);
        ppos[row*256 + t] = pe;
        float pv = tgt[(b*350 + q)*256 + t];
        prop[row*256 + t] = pv;
        q_b[row*256 + t] = f2b(pv + pe);
        if (t < 4) out_pref[row*4 + t] = refp[(b*350 + q)*4 + t];
    } else {
        int r2 = row - ROWS;           // 0..399
        int b = r2 / NTQ, qq = r2 % NTQ;
        tq[r2*256 + t] = f2b(tgt[(b*350 + NQ + qq)*256 + t]);
    }
}

// ---------------- bf16 MFMA GEMM (128x128 tile, double-buffered prefetch) ------
// flags: 1 = relu, 2 = store bf16 (else f32)
__global__ __launch_bounds__(256) void gemm_bt(
    const u16* __restrict__ A, const u16* __restrict__ Bt,
    const float* __restrict__ bias, void* __restrict__ Cout,
    int M, int N, int K, int flags)
{
    __shared__ __align__(16) u16 As[2][128*32];
    __shared__ __align__(16) u16 Bs[2][128*32];
    int tid = threadIdx.x;
    int lane = tid & 63, wave = tid >> 6;
    int bm = blockIdx.y * 128, bn = blockIdx.x * 128;
    int wm = (wave >> 1) * 64, wn = (wave & 1) * 64;
    f32x4 acc[4][4] = {};
    int r = tid >> 2, c = (tid & 3) * 8;
    const u16* Ap0 = A  + (long)min(bm + r,      M-1) * K + c;
    const u16* Ap1 = A  + (long)min(bm + r + 64, M-1) * K + c;
    const u16* Bp0 = Bt + (long)min(bn + r,      N-1) * K + c;
    const u16* Bp1 = Bt + (long)min(bn + r + 64, N-1) * K + c;
    int fr = lane & 15, fk = (lane >> 4) * 8;

    auto STG = [&](int bi, int k0) {
        ASYNC_CP16(&As[bi][tid*8],         Ap0 + k0);
        ASYNC_CP16(&As[bi][64*32 + tid*8], Ap1 + k0);
        ASYNC_CP16(&Bs[bi][tid*8],         Bp0 + k0);
        ASYNC_CP16(&Bs[bi][64*32 + tid*8], Bp1 + k0);
    };
    STG(0, 0);
    asm volatile("s_waitcnt vmcnt(0)" ::: "memory");
    __syncthreads();
    int cur = 0;
    for (int k0 = 0; k0 < K; k0 += 32) {
        if (k0 + 32 < K) STG(cur ^ 1, k0 + 32);   // prefetch hides under compute
        v8bf af[4], bf[4];
        #pragma unroll
        for (int i = 0; i < 4; ++i) af[i] = *(const v8bf*)&As[cur][(wm + i*16 + fr)*32 + fk];
        #pragma unroll
        for (int j = 0; j < 4; ++j) bf[j] = *(const v8bf*)&Bs[cur][(wn + j*16 + fr)*32 + fk];
        #pragma unroll
        for (int i = 0; i < 4; ++i)
            #pragma unroll
            for (int j = 0; j < 4; ++j)
                acc[i][j] = __builtin_amdgcn_mfma_f32_16x16x32_bf16(af[i], bf[j], acc[i][j], 0, 0, 0);
        asm volatile("s_waitcnt vmcnt(0)" ::: "memory");
        __syncthreads();
        cur ^= 1;
    }
    // epilogue: C/D layout col=lane&15, row=(lane>>4)*4+reg  [m89/m91-verified]
    int cq = lane >> 4, cn = lane & 15;
    #pragma unroll
    for (int i = 0; i < 4; ++i) {
        #pragma unroll
        for (int j = 0; j < 4; ++j) {
            int col = bn + wn + j*16 + cn;
            float bv_ = bias ? bias[col] : 0.0f;
            #pragma unroll
            for (int rr = 0; rr < 4; ++rr) {
                int m = bm + wm + i*16 + cq*4 + rr;
                if (m < M) {
                    float v = acc[i][j][rr] + bv_;
                    if (flags & 1) v = fmaxf(v, 0.0f);
                    if (flags & 2) ((u16*)Cout)[(long)m*N + col] = f2b(v);
                    else           ((float*)Cout)[(long)m*N + col] = v;
                }
            }
        }
    }
}

// ---------------- bf16 MFMA GEMM (64x128 tile, dbuf) for small-M GEMMs --------
__global__ __launch_bounds__(256) void gemm_bt64(
    const u16* __restrict__ A, const u16* __restrict__ Bt,
    const float* __restrict__ bias, void* __restrict__ Cout,
    int M, int N, int K, int flags)
{
    __shared__ __align__(16) u16 As[2][64*32];
    __shared__ __align__(16) u16 Bs[2][128*32];
    int tid = threadIdx.x;
    int lane = tid & 63, wave = tid >> 6;
    int bm = blockIdx.y * 64, bn = blockIdx.x * 128;
    int wm = (wave >> 1) * 32, wn = (wave & 1) * 64;
    f32x4 acc[2][4] = {};
    int r = tid >> 2, c = (tid & 3) * 8;
    const u16* Ap0 = A  + (long)min(bm + r,      M-1) * K + c;
    const u16* Bp0 = Bt + (long)min(bn + r,      N-1) * K + c;
    const u16* Bp1 = Bt + (long)min(bn + r + 64, N-1) * K + c;
    int fr = lane & 15, fk = (lane >> 4) * 8;

    auto STG = [&](int bi, int k0) {
        ASYNC_CP16(&As[bi][tid*8],         Ap0 + k0);
        ASYNC_CP16(&Bs[bi][tid*8],         Bp0 + k0);
        ASYNC_CP16(&Bs[bi][64*32 + tid*8], Bp1 + k0);
    };
    STG(0, 0);
    asm volatile("s_waitcnt vmcnt(0)" ::: "memory");
    __syncthreads();
    int cur = 0;
    for (int k0 = 0; k0 < K; k0 += 32) {
        if (k0 + 32 < K) STG(cur ^ 1, k0 + 32);
        v8bf af[2], bf[4];
        #pragma unroll
        for (int i = 0; i < 2; ++i) af[i] = *(const v8bf*)&As[cur][(wm + i*16 + fr)*32 + fk];
        #pragma unroll
        for (int j = 0; j < 4; ++j) bf[j] = *(const v8bf*)&Bs[cur][(wn + j*16 + fr)*32 + fk];
        #pragma unroll
        for (int i = 0; i < 2; ++i)
            #pragma unroll
            for (int j = 0; j < 4; ++j)
                acc[i][j] = __builtin_amdgcn_mfma_f32_16x16x32_bf16(af[i], bf[j], acc[i][j], 0, 0, 0);
        asm volatile("s_waitcnt vmcnt(0)" ::: "memory");
        __syncthreads();
        cur ^= 1;
    }
    int cq = lane >> 4, cn = lane & 15;
    #pragma unroll
    for (int i = 0; i < 2; ++i) {
        #pragma unroll
        for (int j = 0; j < 4; ++j) {
            int col = bn + wn + j*16 + cn;
            float bv_ = bias ? bias[col] : 0.0f;
            #pragma unroll
            for (int rr = 0; rr < 4; ++rr) {
                int m = bm + wm + i*16 + cq*4 + rr;
                if (m < M) {
                    float v = acc[i][j][rr] + bv_;
                    if (flags & 1) v = fmaxf(v, 0.0f);
                    if (flags & 2) ((u16*)Cout)[(long)m*N + col] = f2b(v);
                    else           ((float*)Cout)[(long)m*N + col] = v;
                }
            }
        }
    }
}

// ---------------- batched value GEMM v2: B-stationary, barrier-free ------------
// value_l = src_b @ Wv_l^T for l=0..5. Grid 3792 = 316 row-groups x 12 (layer,
// col-half). Per block: full 128x256 B col-tile staged ONCE into chunk-major
// LDS [ks][kchunk][col][8] (conflict-free ds_read_b128: consecutive lanes hit
// consecutive bank quads), staged via CP16 with pre-permuted per-lane global
// source (m173). A-fragments load global->register directly (per-lane 16B,
// 16 rows x 64B = full cache lines). NO barriers in the K-loop.
// 4 row-tiles per block amortize the B stage. XCD-bijective swizzle keeps the
// 12 blocks of one row-group on one XCD (A L2 reuse).
__global__ __launch_bounds__(256, 2) void gemm_value6_v2(
    const u16* __restrict__ A, const u16* __restrict__ wtall,
    const float* __restrict__ biasall, u16* __restrict__ Cout)
{
    __shared__ __align__(16) u16 Bsw[8*4*128*8];   // 64 KB
    int bid = blockIdx.x;
    int xcd = bid & 7, sl = bid >> 3;
    int wgid = xcd*474 + sl;              // nwg = 3792 = 8*474 exactly (bijective)
    int rg = wgid / 12, zx = wgid % 12;
    int z = zx >> 1, half = zx & 1;
    int bn = half*128;
    long rowbase0 = (long)rg * 512;       // 4 tiles x 128 rows
    const u16* Bt = wtall + (size_t)z*884736 + 98304;   // wv_t of layer z
    const float* bs = biasall + z*2688 + 384;           // bv of layer z
    u16* Cz = Cout + (size_t)z*((size_t)MVAL*256);

    int tid = threadIdx.x;
    int lane = tid & 63;
    int wave = tid >> 6;
    int fr = lane & 15, q = lane >> 4;    // frag row index, k-chunk

    // ---- stage B: LDS element layout idx = ks*4096 + chunk*1024 + col*8 ----
    // dest byte offset = (it*256+tid)*16 = wave-uniform base + lane*16  [OK]
    #pragma unroll
    for (int it = 0; it < 16; ++it) {
        int c_id = it*256 + tid;          // 16B-chunk index, 0..4095
        int col   = c_id & 127;
        int chunk = (c_id >> 7) & 3;
        int ks    = c_id >> 9;
        const u16* srcp = Bt + (size_t)(bn + col)*256 + ks*32 + chunk*8;
        ASYNC_CP16(&Bsw[(size_t)c_id*8], srcp);
    }
    asm volatile("s_waitcnt vmcnt(0)" ::: "memory");
    __syncthreads();

    float bcache[8];
    #pragma unroll
    for (int j = 0; j < 8; ++j) bcache[j] = bs[bn + j*16 + fr];

    for (int rt = 0; rt < 4; ++rt) {
        long rowb = rowbase0 + rt*128 + wave*32;   // wave owns 32 rows
        const u16* Arow0 = A + (long)min(rowb + fr,      (long)(MVAL-1))*256 + q*8;
        const u16* Arow1 = A + (long)min(rowb + 16 + fr, (long)(MVAL-1))*256 + q*8;
        f32x4 acc[2][8] = {};
        #pragma unroll
        for (int ks = 0; ks < 8; ++ks) {
            v8bf a0 = *(const v8bf*)(Arow0 + ks*32);
            v8bf a1 = *(const v8bf*)(Arow1 + ks*32);
            v8bf bf[8];
            #pragma unroll
            for (int j = 0; j < 8; ++j)
                bf[j] = *(const v8bf*)&Bsw[ks*4096 + q*1024 + (j*16 + fr)*8];
            #pragma unroll
            for (int j = 0; j < 8; ++j) {
                acc[0][j] = __builtin_amdgcn_mfma_f32_16x16x32_bf16(a0, bf[j], acc[0][j], 0, 0, 0);
                acc[1][j] = __builtin_amdgcn_mfma_f32_16x16x32_bf16(a1, bf[j], acc[1][j], 0, 0, 0);
            }
        }
        // epilogue: C/D layout col=lane&15, row=(lane>>4)*4+rr
        #pragma unroll
        for (int j = 0; j < 8; ++j) {
            int col = bn + j*16 + fr;
            float bv_ = bcache[j];
            #pragma unroll
            for (int rr = 0; rr < 4; ++rr) {
                long m0 = rowb + q*4 + rr;
                long m1 = rowb + 16 + q*4 + rr;
                if (m0 < MVAL) Cz[m0*256 + col] = f2b(acc[0][j][rr] + bv_);
                if (m1 < MVAL) Cz[m1*256 + col] = f2b(acc[1][j][rr] + bv_);
            }
        }
    }
}

// ---------------- fused softmax+locations (LDS) + vectorized bilinear gather ----
__global__ __launch_bounds__(256) void sample_fused(
    const u16* __restrict__ value, const float* __restrict__ offatt,
    const float* __restrict__ refp, const float* __restrict__ svr,
    u16* __restrict__ sampout)
{
    int row = blockIdx.x, t = threadIdx.x;
    int b = row / NQ, q = row % NQ;
    __shared__ float lg[128], awl[128], sxl[128], syl[128];
    const int WL[4] = {152,76,38,19}, HL[4] = {100,50,25,13}, LS[4] = {0,15200,19000,19950};

    if (t < 128) lg[t] = offatt[row*384 + 256 + t];
    __syncthreads();
    if (t < 128) {
        int h = t >> 4, s = t & 15, lvl = s >> 2, pp = s & 3;
        int gb = h << 4;
        float mx = -1e30f;
        for (int i = 0; i < 16; ++i) mx = fmaxf(mx, lg[gb + i]);
        float sm = 0.f;
        for (int i = 0; i < 16; ++i) sm += expf(lg[gb + i] - mx);
        awl[t] = expf(lg[t] - mx) / sm;
        float rx = refp[(b*350+q)*4 + 0] * svr[(b*4+lvl)*2 + 0];
        float ry = refp[(b*350+q)*4 + 1] * svr[(b*4+lvl)*2 + 1];
        float rw = refp[(b*350+q)*4 + 2] * svr[(b*4+lvl)*2 + 0];
        float rh = refp[(b*350+q)*4 + 3] * svr[(b*4+lvl)*2 + 1];
        float ox = offatt[row*384 + h*32 + lvl*8 + pp*2 + 0];
        float oy = offatt[row*384 + h*32 + lvl*8 + pp*2 + 1];
        sxl[t] = (rx + ox * 0.25f * rw * 0.5f) * (float)WL[lvl] - 0.5f;
        syl[t] = (ry + oy * 0.25f * rh * 0.5f) * (float)HL[lvl] - 0.5f;
    }
    __syncthreads();

    int lane = t & 63, wv = t >> 6;
    int g = lane >> 3, e = lane & 7;       // group handles one corner; lane -> 4 channels
    for (int hh = 0; hh < 2; ++hh) {
        int h = wv*2 + hh;
        float a0 = 0.f, a1 = 0.f, a2 = 0.f, a3 = 0.f;
        #pragma unroll
        for (int it = 0; it < 8; ++it) {
            int task = it*8 + g;           // 0..63 = s*4 + corner
            int s = task >> 2, cc = task & 3;
            int cx = cc & 1, cy = cc >> 1;
            int lvl = s >> 2;
            float x = sxl[h*16 + s], y2 = syl[h*16 + s], aw = awl[h*16 + s];
            float x0 = floorf(x), y0 = floorf(y2);
            float xc = x0 + (float)cx, yc = y0 + (float)cy;
            int wl = WL[lvl], hl = HL[lvl];
            if (xc >= 0.f && xc <= (float)(wl-1) && yc >= 0.f && yc <= (float)(hl-1)) {
                float lx = x - x0, ly = y2 - y0;
                float wgt = aw * (cx ? lx : 1.f - lx) * (cy ? ly : 1.f - ly);
                long off = ((long)b*S_TOTAL + LS[lvl] + (int)yc*wl + (int)xc)*256 + h*32 + e*4;
                uint2 v = *(const uint2*)(value + off);
                a0 += wgt * __uint_as_float((v.x & 0xffffu) << 16);
                a1 += wgt * __uint_as_float(v.x & 0xffff0000u);
                a2 += wgt * __uint_as_float((v.y & 0xffffu) << 16);
                a3 += wgt * __uint_as_float(v.y & 0xffff0000u);
            }
        }
        #pragma unroll
        for (int o = 8; o < 64; o <<= 1) {
            a0 += __shfl_xor(a0, o); a1 += __shfl_xor(a1, o);
            a2 += __shfl_xor(a2, o); a3 += __shfl_xor(a3, o);
        }
        if (g == 0)
            *(uint2*)&sampout[row*256 + h*32 + e*4] = make_uint2(pk2(a0, a1), pk2(a2, a3));
    }
}

// ---------------- residual + layernorm (writes f32 master + bf16 copy + q) -----
__global__ void ln_kernel(float* __restrict__ prop, const float* __restrict__ delta,
                          const float* __restrict__ w, const float* __restrict__ bsh,
                          u16* __restrict__ pb_out, u16* __restrict__ q_out,
                          const float* __restrict__ ppos)
{
    int row = blockIdx.x, t = threadIdx.x;
    int lane = t & 63, wv = t >> 6;
    float v = prop[row*256 + t] + delta[row*256 + t];
    float s = v;
    for (int o = 32; o; o >>= 1) s += __shfl_xor(s, o);
    __shared__ float red[4], red2[4];
    if (lane == 0) red[wv] = s;
    __syncthreads();
    float mean = (red[0]+red[1]+red[2]+red[3]) * (1.0f/256.0f);
    float dd = v - mean;
    float s2 = dd * dd;
    for (int o = 32; o; o >>= 1) s2 += __shfl_xor(s2, o);
    if (lane == 0) red2[wv] = s2;
    __syncthreads();
    float var = (red2[0]+red2[1]+red2[2]+red2[3]) * (1.0f/256.0f);
    float nv = dd * rsqrtf(var + 1e-5f) * w[t] + bsh[t];
    prop[row*256 + t] = nv;
    pb_out[row*256 + t] = f2b(nv);
    if (q_out) q_out[row*256 + t] = f2b(nv + ppos[row*256 + t]);
}

// ---------------- qk convert: f32 -> bf16 + per-head norms ---------------------
__global__ __launch_bounds__(128) void qk_convert(
    const float* __restrict__ qkp, const float* __restrict__ kt,
    u16* __restrict__ qk_b, u16* __restrict__ kt_b,
    float* __restrict__ qn_g, float* __restrict__ knp_g, float* __restrict__ knt_g)
{
    int row = blockIdx.x, t = threadIdx.x;
    __shared__ float part[128];
    if (row < ROWS) {
        const float* sp = qkp + (long)row*512 + t*4;
        float4 v = *(const float4*)sp;
        *(uint2*)&qk_b[(long)row*512 + t*4] = make_uint2(pk2(v.x,v.y), pk2(v.z,v.w));
        part[t] = v.x*v.x + v.y*v.y + v.z*v.z + v.w*v.w;
        __syncthreads();
        if (t < 4) {
            float s = 0.f;
            for (int i = 0; i < 32; ++i) s += part[t*32 + i];
            int b = row / NQ, q = row % NQ;
            float nv = sqrtf(s) + 1e-6f;
            if      (t == 0) qn_g [(b*2+0)*NQ + q] = nv;
            else if (t == 1) qn_g [(b*2+1)*NQ + q] = nv;
            else if (t == 2) knp_g[(b*2+0)*NQ + q] = nv;
            else             knp_g[(b*2+1)*NQ + q] = nv;
        }
    } else {
        int r2 = row - ROWS;                 // 0..399
        float ss = 0.f;
        if (t < 64) {
            const float* sp = kt + (long)r2*256 + t*4;
            float4 v = *(const float4*)sp;
            *(uint2*)&kt_b[(long)r2*256 + t*4] = make_uint2(pk2(v.x,v.y), pk2(v.z,v.w));
            ss = v.x*v.x + v.y*v.y + v.z*v.z + v.w*v.w;
        }
        part[t] = ss;
        __syncthreads();
        if (t < 2) {
            float s = 0.f;
            for (int i = 0; i < 32; ++i) s += part[t*32 + i];
            int b = r2 / NTQ, qq = r2 % NTQ;
            knt_g[(b*2+t)*NTQ + qq] = sqrtf(s) + 1e-6f;
        }
    }
}

// ---------------- weight_attn via MFMA: S=Q.K^T; cos + raw logits --------------
__global__ __launch_bounds__(256) void wattn_mfma(
    const u16* __restrict__ Qb, const u16* __restrict__ Kb,
    int qstride, int kstride, int koff, int nk,
    const float* __restrict__ qn_g, const float* __restrict__ kn_g,
    float* __restrict__ out_cos, float* __restrict__ out_logit)
{
    __shared__ __align__(16) u16 As[2][128*32];
    __shared__ __align__(16) u16 Bs[2][128*32];
    int bh = blockIdx.z, b = bh >> 1, h = bh & 1;
    int tid = threadIdx.x;
    int lane = tid & 63, wave = tid >> 6;
    int bm = blockIdx.y * 128, bn = blockIdx.x * 128;
    int wm = (wave >> 1) * 64, wn = (wave & 1) * 64;
    f32x4 acc[4][4] = {};
    int r = tid >> 2, c = (tid & 3) * 8;
    const u16* Ap0 = Qb + (long)(b*NQ + min(bm + r,      NQ-1))*qstride + h*128 + c;
    const u16* Ap1 = Qb + (long)(b*NQ + min(bm + r + 64, NQ-1))*qstride + h*128 + c;
    const u16* Bp0 = Kb + (long)(b*nk + min(bn + r,      nk-1))*kstride + koff + h*128 + c;
    const u16* Bp1 = Kb + (long)(b*nk + min(bn + r + 64, nk-1))*kstride + koff + h*128 + c;
    int fr = lane & 15, fk = (lane >> 4) * 8;

    auto STG = [&](int bi, int k0) {
        ASYNC_CP16(&As[bi][tid*8],         Ap0 + k0);
        ASYNC_CP16(&As[bi][64*32 + tid*8], Ap1 + k0);
        ASYNC_CP16(&Bs[bi][tid*8],         Bp0 + k0);
        ASYNC_CP16(&Bs[bi][64*32 + tid*8], Bp1 + k0);
    };
    STG(0, 0);
    asm volatile("s_waitcnt vmcnt(0)" ::: "memory");
    __syncthreads();
    int cur = 0;
    for (int k0 = 0; k0 < 128; k0 += 32) {
        if (k0 + 32 < 128) STG(cur ^ 1, k0 + 32);
        v8bf af[4], bf[4];
        #pragma unroll
        for (int i = 0; i < 4; ++i) af[i] = *(const v8bf*)&As[cur][(wm + i*16 + fr)*32 + fk];
        #pragma unroll
        for (int j = 0; j < 4; ++j) bf[j] = *(const v8bf*)&Bs[cur][(wn + j*16 + fr)*32 + fk];
        #pragma unroll
        for (int i = 0; i < 4; ++i)
            #pragma unroll
            for (int j = 0; j < 4; ++j)
                acc[i][j] = __builtin_amdgcn_mfma_f32_16x16x32_bf16(af[i], bf[j], acc[i][j], 0, 0, 0);
        asm volatile("s_waitcnt vmcnt(0)" ::: "memory");
        __syncthreads();
        cur ^= 1;
    }
    const float SC = 0.08838834764831845f;   // 1/sqrt(128)
    int cq = lane >> 4, cn = lane & 15;
    #pragma unroll
    for (int i = 0; i < 4; ++i) {
        #pragma unroll
        for (int j = 0; j < 4; ++j) {
            int col = bn + wn + j*16 + cn;
            #pragma unroll
            for (int rr = 0; rr < 4; ++rr) {
                int m = bm + wm + i*16 + cq*4 + rr;
                if (m < NQ && col < nk) {
                    float d = acc[i][j][rr];
                    long o = ((long)(bh*NQ + m))*nk + col;
                    out_cos[o]   = d / (qn_g[bh*NQ + m] * kn_g[bh*nk + col]);
                    out_logit[o] = d * SC;
                }
            }
        }
    }
}

// ---------------- in-place row softmax over nk ---------------------------------
__global__ __launch_bounds__(64) void row_softmax(float* __restrict__ buf, int nk)
{
    long row = blockIdx.x;
    float* p = buf + row*nk;
    int lane = threadIdx.x;
    float mx = -1e30f;
    for (int k = lane; k < nk; k += 64) mx = fmaxf(mx, p[k]);
    for (int o = 32; o; o >>= 1) mx = fmaxf(mx, __shfl_xor(mx, o));
    float s = 0.f;
    for (int k = lane; k < nk; k += 64) s += expf(p[k] - mx);
    for (int o = 32; o; o >>= 1) s += __shfl_xor(s, o);
    float inv = 1.0f / s;
    for (int k = lane; k < nk; k += 64) p[k] = expf(p[k] - mx) * inv;
}

__global__ void writeout_kernel(const float* __restrict__ prop, float* __restrict__ out)
{
    int row = blockIdx.x, t = threadIdx.x;
    out[row*256 + t] = prop[row*256 + t];
}

// ---------------- host launcher ----------------
extern "C" void kernel_launch(void* const* d_in, const int* in_sizes, int n_in,
                              void* d_out, int out_size, void* d_ws, size_t ws_size,
                              hipStream_t stream)
{
    (void)in_sizes; (void)n_in; (void)out_size; (void)ws_size;
    const float* tgt  = (const float*)d_in[0];
    const float* refp = (const float*)d_in[1];
    const float* src  = (const float*)d_in[2];
    const float* svr  = (const float*)d_in[5];
    const float* Woff = (const float*)d_in[7];
    const float* boff = (const float*)d_in[8];
    const float* Wa   = (const float*)d_in[9];
    const float* ba   = (const float*)d_in[10];
    const float* Wv   = (const float*)d_in[11];
    const float* bv   = (const float*)d_in[12];
    const float* Wout = (const float*)d_in[13];
    const float* bout = (const float*)d_in[14];
    const float* Wl1  = (const float*)d_in[15];
    const float* bl1  = (const float*)d_in[16];
    const float* Wl2  = (const float*)d_in[17];
    const float* bl2  = (const float*)d_in[18];
    const float* Wq   = (const float*)d_in[19];
    const float* bq   = (const float*)d_in[20];
    const float* Wk   = (const float*)d_in[21];
    const float* bk   = (const float*)d_in[22];
    const float* n1w  = (const float*)d_in[23];
    const float* n1b  = (const float*)d_in[24];
    const float* n3w  = (const float*)d_in[25];
    const float* n3b  = (const float*)d_in[26];
    float* out = (float*)d_out;

    char* p = (char*)d_ws;
    auto alloc = [&](size_t bytes) { void* r = (void*)p; p += (bytes + 255) & ~(size_t)255; return r; };
    u16*   wt      = (u16*)  alloc(6ull*884736*2);       // 10.6 MB
    float* bias    = (float*)alloc(6ull*2688*4);
    u16*   value   = (u16*)  alloc(6ull*MVAL*256*2);     // 496 MB (all 6 layers)
    u16*   src_b   = (u16*)  alloc((size_t)MVAL*256*2);  // 82.7 MB
    float* prop    = (float*)alloc((size_t)ROWS*256*4);
    u16*   prop_b  = (u16*)  alloc((size_t)ROWS*256*2);
    u16*   q_b     = (u16*)  alloc((size_t)ROWS*256*2);
    float* ppos    = (float*)alloc((size_t)ROWS*256*4);
    float* offatt  = (float*)alloc((size_t)ROWS*384*4);
    u16*   sampout = (u16*)  alloc((size_t)ROWS*256*2);
    float* ca      = (float*)alloc((size_t)ROWS*256*4);
    u16*   ff1     = (u16*)  alloc((size_t)ROWS*1024*2);
    float* ff2     = (float*)alloc((size_t)ROWS*256*4);
    u16*   tq      = (u16*)  alloc(400ull*256*2);
    float* qkp     = (float*)alloc((size_t)ROWS*512*4);
    float* kt      = (float*)alloc(400ull*256*4);
    u16*   qk_b    = (u16*)  alloc((size_t)ROWS*512*2);
    u16*   kt_b    = (u16*)  alloc(400ull*256*2);
    float* qn_g    = (float*)alloc(16ull*NQ*4);
    float* knp_g   = (float*)alloc(16ull*NQ*4);
    float* knt_g   = (float*)alloc(16ull*NTQ*4);

    transpose_pack<<<20799, 256, 0, stream>>>(Woff, Wa, Wv, Wout, Wl1, Wl2, Wq, Wk,
                                              boff, ba, bv, bout, bl1, bl2, bq, bk, wt, bias);
    src_convert<<<20197, 256, 0, stream>>>(src, src_b);
    setup_kernel<<<ROWS + 400, 256, 0, stream>>>(tgt, refp, prop, q_b, ppos, tq, out + 614400);
    // all 6 layers' value projections in one barrier-free B-stationary dispatch
    gemm_value6_v2<<<3792, 256, 0, stream>>>(src_b, wt, bias, value);

    for (int l = 0; l < NLAY; ++l) {
        const u16* wl_ = wt + (size_t)l*884736;
        const float* bl_ = bias + l*2688;
        gemm_bt64<<<dim3(3, 38), 256, 0, stream>>>(q_b,    wl_,          bl_,        offatt, ROWS, 384, 256, 0);
        sample_fused<<<ROWS, 256, 0, stream>>>(value + (size_t)l*MVAL*256, offatt, refp, svr, sampout);
        gemm_bt64<<<dim3(2, 38), 256, 0, stream>>>(sampout, wl_ + 163840, bl_ + 640,  ca,    ROWS, 256, 256, 0);
        ln_kernel<<<ROWS, 256, 0, stream>>>(prop, ca, n1w + l*256, n1b + l*256, prop_b, (u16*)nullptr, ppos);
        gemm_bt64<<<dim3(8, 38), 256, 0, stream>>>(prop_b, wl_ + 229376, bl_ + 896,  ff1,   ROWS, 1024, 256, 3);
        gemm_bt64<<<dim3(2, 38), 256, 0, stream>>>(ff1,    wl_ + 491520, bl_ + 1920, ff2,   ROWS, 256, 1024, 0);
        ln_kernel<<<ROWS, 256, 0, stream>>>(prop, ff2, n3w + l*256, n3b + l*256, prop_b, q_b, ppos);
    }

    const u16* w5 = wt + 5ull*884736;
    const float* b5 = bias + 5*2688;
    gemm_bt64<<<dim3(4, 38), 256, 0, stream>>>(prop_b, w5 + 753664,         b5 + 2176,       qkp, ROWS, 512, 256, 0);
    gemm_bt64<<<dim3(2, 7),  256, 0, stream>>>(tq,     w5 + 753664 + 65536, b5 + 2176 + 256, kt,  400,  256, 256, 0);
    qk_convert<<<2800, 128, 0, stream>>>(qkp, kt, qk_b, kt_b, qn_g, knp_g, knt_g);
    // pt: K from track queries (kt_b, stride 256, koff 0, nk=50)
    wattn_mfma<<<dim3(1, 3, 16), 256, 0, stream>>>(qk_b, kt_b, 512, 256, 0,   NTQ, qn_g, knt_g,
                                                   out + 624000, out + 2304000);
    // pp: K from proposals (qk_b, stride 512, koff 256, nk=300)
    wattn_mfma<<<dim3(3, 3, 16), 256, 0, stream>>>(qk_b, qk_b, 512, 512, 256, NQ,  qn_g, knp_g,
                                                   out + 864000, out + 2544000);
    row_softmax<<<4800, 64, 0, stream>>>(out + 2304000, NTQ);
    row_softmax<<<4800, 64, 0, stream>>>(out + 2544000, NQ);
    writeout_kernel<<<ROWS, 256, 0, stream>>>(prop, out);
}

// Round 5
// 1288.820 us; speedup vs baseline: 1.2304x; 1.2304x over previous
//
#include <hip/hip_runtime.h>

// ---------------- problem constants ----------------
#define BB 8
#define NQ 300
#define NTQ 50
#define NLAY 6
#define S_TOTAL 20197
#define ROWS (BB*NQ)        // 2400
#define MVAL (BB*S_TOTAL)   // 161576

typedef unsigned short u16;
typedef unsigned int u32;
typedef __bf16 v8bf __attribute__((ext_vector_type(8)));
typedef float f32x4 __attribute__((ext_vector_type(4)));

__device__ __forceinline__ u16 f2b(float f) {
    u32 u = __float_as_uint(f);
    u32 r = (u + 0x7fffu + ((u >> 16) & 1u)) >> 16;
    return (u16)r;
}
__device__ __forceinline__ u32 pk2(float lo, float hi) {
    return (u32)f2b(lo) | ((u32)f2b(hi) << 16);
}

// async global->LDS 16B/lane. LDS dest must be wave-uniform base + lane*16;
// global source address is per-lane (m173: pre-permuted source enables
// arbitrary LDS layouts while keeping the destination linear).
#define ASYNC_CP16(dst_lds, src_g) \
    __builtin_amdgcn_global_load_lds((const __attribute__((address_space(1))) u32*)(src_g), \
                                     (__attribute__((address_space(3))) u32*)(dst_lds), 16, 0, 0)

// ---------------- weight transpose (f32 -> bf16) + bias pack ----------------
// wt layout per layer (element offsets, layer stride 884736):
//   [0) offa_t 384x256 | [98304) wv_t 256x256 | [163840) wout_t 256x256
//   [229376) wl1_t 1024x256 | [491520) wl2_t 256x1024 | [753664) wqk_t 512x256
// bias f32 per layer (stride 2688): boffa[0) bv[384) bout[640) bl1[896) bl2[1920) bqk[2176)
__global__ void transpose_pack(
    const float* Woff, const float* Wa, const float* Wv, const float* Wout,
    const float* Wl1, const float* Wl2, const float* Wq, const float* Wk,
    const float* boff, const float* ba, const float* bvp, const float* bout,
    const float* bl1, const float* bl2, const float* bq, const float* bk,
    u16* wt, float* bias)
{
    int idx = blockIdx.x * 256 + threadIdx.x;
    if (idx < 5308416) {
        int l = idx / 884736;
        int o = idx % 884736;
        float v;
        if (o < 98304) { int n = o >> 8, k = o & 255;
            v = (n < 256) ? Woff[l*65536 + k*256 + n] : Wa[l*32768 + k*128 + (n-256)];
        } else if (o < 163840) { int o2 = o - 98304; int n = o2 >> 8, k = o2 & 255;
            v = Wv[l*65536 + k*256 + n];
        } else if (o < 229376) { int o2 = o - 163840; int n = o2 >> 8, k = o2 & 255;
            v = Wout[l*65536 + k*256 + n];
        } else if (o < 491520) { int o2 = o - 229376; int n = o2 >> 8, k = o2 & 255;
            v = Wl1[l*262144 + k*1024 + n];
        } else if (o < 753664) { int o2 = o - 491520; int n = o2 >> 10, k = o2 & 1023;
            v = Wl2[l*262144 + k*256 + n];
        } else { int o2 = o - 753664; int n = o2 >> 8, k = o2 & 255;
            v = (n < 256) ? Wq[l*65536 + k*256 + n] : Wk[l*65536 + k*256 + (n-256)];
        }
        wt[idx] = f2b(v);
    } else {
        int i2 = idx - 5308416;
        if (i2 < 16128) {
            int l = i2 / 2688, o = i2 % 2688;
            float v;
            if (o < 256)       v = boff[l*256 + o];
            else if (o < 384)  v = ba  [l*128 + (o-256)];
            else if (o < 640)  v = bvp [l*256 + (o-384)];
            else if (o < 896)  v = bout[l*256 + (o-640)];
            else if (o < 1920) v = bl1 [l*1024 + (o-896)];
            else if (o < 2176) v = bl2 [l*256 + (o-1920)];
            else if (o < 2432) v = bq  [l*256 + (o-2176)];
            else               v = bk  [l*256 + (o-2432)];
            bias[i2] = v;
        }
    }
}

// ---------------- src f32 -> bf16 (once; reused by the batched value GEMM) ----
__global__ void src_convert(const float* __restrict__ src, u16* __restrict__ dst)
{
    long i = ((long)blockIdx.x*256 + threadIdx.x)*8;
    float4 a = *(const float4*)(src+i), b4 = *(const float4*)(src+i+4);
    uint4 o = make_uint4(pk2(a.x,a.y), pk2(a.z,a.w), pk2(b4.x,b4.y), pk2(b4.z,b4.w));
    *(uint4*)&dst[i] = o;
}

// ---------------- setup: p_pos, proposals init, layer-0 q, p_ref out, tq pack ----
__global__ void setup_kernel(const float* tgt, const float* refp, float* prop,
                             u16* q_b, float* ppos, u16* tq, float* out_pref)
{
    int row = blockIdx.x, t = threadIdx.x;
    if (row < ROWS) {
        int b = row / NQ, q = row % NQ;
        int k = t >> 6, rem = t & 63, j = rem >> 1;
        float pr = refp[(b*350 + q)*4 + k];
        float dimt = powf(10000.0f, (float)j * (1.0f/32.0f));
        float arg = pr * 6.283185307179586f / dimt;
        float pe = (rem & 1) ? cosf(arg) : sinf(arg);
        ppos[row*256 + t] = pe;
        float pv = tgt[(b*350 + q)*256 + t];
        prop[row*256 + t] = pv;
        q_b[row*256 + t] = f2b(pv + pe);
        if (t < 4) out_pref[row*4 + t] = refp[(b*350 + q)*4 + t];
    } else {
        int r2 = row - ROWS;           // 0..399
        int b = r2 / NTQ, qq = r2 % NTQ;
        tq[r2*256 + t] = f2b(tgt[(b*350 + NQ + qq)*256 + t]);
    }
}

// ---------------- bf16 MFMA GEMM (64x128 tile, dbuf) for small-M GEMMs --------
__global__ __launch_bounds__(256) void gemm_bt64(
    const u16* __restrict__ A, const u16* __restrict__ Bt,
    const float* __restrict__ bias, void* __restrict__ Cout,
    int M, int N, int K, int flags)
{
    __shared__ __align__(16) u16 As[2][64*32];
    __shared__ __align__(16) u16 Bs[2][128*32];
    int tid = threadIdx.x;
    int lane = tid & 63, wave = tid >> 6;
    int bm = blockIdx.y * 64, bn = blockIdx.x * 128;
    int wm = (wave >> 1) * 32, wn = (wave & 1) * 64;
    f32x4 acc[2][4] = {};
    int r = tid >> 2, c = (tid & 3) * 8;
    const u16* Ap0 = A  + (long)min(bm + r,      M-1) * K + c;
    const u16* Bp0 = Bt + (long)min(bn + r,      N-1) * K + c;
    const u16* Bp1 = Bt + (long)min(bn + r + 64, N-1) * K + c;
    int fr = lane & 15, fk = (lane >> 4) * 8;

    auto STG = [&](int bi, int k0) {
        ASYNC_CP16(&As[bi][tid*8],         Ap0 + k0);
        ASYNC_CP16(&Bs[bi][tid*8],         Bp0 + k0);
        ASYNC_CP16(&Bs[bi][64*32 + tid*8], Bp1 + k0);
    };
    STG(0, 0);
    asm volatile("s_waitcnt vmcnt(0)" ::: "memory");
    __syncthreads();
    int cur = 0;
    for (int k0 = 0; k0 < K; k0 += 32) {
        if (k0 + 32 < K) STG(cur ^ 1, k0 + 32);
        v8bf af[2], bf[4];
        #pragma unroll
        for (int i = 0; i < 2; ++i) af[i] = *(const v8bf*)&As[cur][(wm + i*16 + fr)*32 + fk];
        #pragma unroll
        for (int j = 0; j < 4; ++j) bf[j] = *(const v8bf*)&Bs[cur][(wn + j*16 + fr)*32 + fk];
        #pragma unroll
        for (int i = 0; i < 2; ++i)
            #pragma unroll
            for (int j = 0; j < 4; ++j)
                acc[i][j] = __builtin_amdgcn_mfma_f32_16x16x32_bf16(af[i], bf[j], acc[i][j], 0, 0, 0);
        asm volatile("s_waitcnt vmcnt(0)" ::: "memory");
        __syncthreads();
        cur ^= 1;
    }
    int cq = lane >> 4, cn = lane & 15;
    #pragma unroll
    for (int i = 0; i < 2; ++i) {
        #pragma unroll
        for (int j = 0; j < 4; ++j) {
            int col = bn + wn + j*16 + cn;
            float bv_ = bias ? bias[col] : 0.0f;
            #pragma unroll
            for (int rr = 0; rr < 4; ++rr) {
                int m = bm + wm + i*16 + cq*4 + rr;
                if (m < M) {
                    float v = acc[i][j][rr] + bv_;
                    if (flags & 1) v = fmaxf(v, 0.0f);
                    if (flags & 2) ((u16*)Cout)[(long)m*N + col] = f2b(v);
                    else           ((float*)Cout)[(long)m*N + col] = v;
                }
            }
        }
    }
}

// ---------------- batched value GEMM v3: A-stationary ------------------------
// value_l = src_b @ Wv_l^T for l=0..5. Grid 1263 row-tiles; each block OWNS its
// 128 A-rows: stages them into LDS once (chunk-major [ks][q][row][8], the
// layout v2 verified conflict-free), then loops over 12 (layer, col-half)
// B-tiles with the proven v1 K-step (dbuf B staging + vmcnt(0)+barrier).
// A is read from HBM exactly once BY CONSTRUCTION (no cross-block L2 reuse
// needed -- the v2 failure mode). B (768 KB total) is L2-resident.
__global__ __launch_bounds__(256, 2) void gemm_value6_v3(
    const u16* __restrict__ A, const u16* __restrict__ wtall,
    const float* __restrict__ biasall, u16* __restrict__ Cout)
{
    __shared__ __align__(16) u16 Asw[8*4*128*8];     // 64 KB  [ks][q][row][8]
    __shared__ __align__(16) u16 Bsw[2][4*128*8];    // 2x8 KB [q][col][8]
    int tid = threadIdx.x;
    int lane = tid & 63, wave = tid >> 6;
    int fr = lane & 15, q = lane >> 4;
    int wm = (wave >> 1) * 64, wn = (wave & 1) * 64;
    long rowb = (long)blockIdx.x * 128;

    // ---- stage A once: chunk-major; dest linear (base + lane*16), src permuted
    #pragma unroll
    for (int it = 0; it < 16; ++it) {
        int c_id = it*256 + tid;            // 0..4095
        int row   = c_id & 127;
        int chunk = (c_id >> 7) & 3;
        int ks    = c_id >> 9;
        const u16* srcp = A + (long)min(rowb + row, (long)(MVAL-1))*256 + ks*32 + chunk*8;
        ASYNC_CP16(&Asw[(size_t)c_id*8], srcp);
    }
    // ---- stage B for step 0 (tile 0, ks 0)
    {
        #pragma unroll
        for (int it = 0; it < 2; ++it) {
            int c_id = it*256 + tid;        // 0..511
            int col   = c_id & 127;
            int chunk = c_id >> 7;
            const u16* srcp = wtall + 98304 + (size_t)col*256 + chunk*8;
            ASYNC_CP16(&Bsw[0][(size_t)c_id*8], srcp);
        }
    }
    asm volatile("s_waitcnt vmcnt(0)" ::: "memory");
    __syncthreads();

    int buf = 0;
    for (int t = 0; t < 12; ++t) {
        int z = t >> 1, half = t & 1;
        u16* Cz = Cout + (size_t)z*((size_t)MVAL*256);
        const float* bs = biasall + z*2688 + 384 + half*128;
        float bc0 = bs[wn + fr], bc1 = bs[wn + 16 + fr],
              bc2 = bs[wn + 32 + fr], bc3 = bs[wn + 48 + fr];
        f32x4 acc[4][4] = {};
        #pragma unroll
        for (int ks = 0; ks < 8; ++ks) {
            int s = t*8 + ks;
            if (s < 95) {                    // stage next step's B chunk
                int sn = s + 1;
                int zn = sn >> 4, halfn = (sn >> 3) & 1, ksn = sn & 7;
                const u16* Bt = wtall + (size_t)zn*884736 + 98304;
                #pragma unroll
                for (int it = 0; it < 2; ++it) {
                    int c_id = it*256 + tid;
                    int col   = c_id & 127;
                    int chunk = c_id >> 7;
                    const u16* srcp = Bt + (size_t)(halfn*128 + col)*256 + ksn*32 + chunk*8;
                    ASYNC_CP16(&Bsw[buf ^ 1][(size_t)c_id*8], srcp);
                }
            }
            v8bf af[4], bf[4];
            #pragma unroll
            for (int i = 0; i < 4; ++i)
                af[i] = *(const v8bf*)&Asw[ks*4096 + q*1024 + (wm + i*16 + fr)*8];
            #pragma unroll
            for (int j = 0; j < 4; ++j)
                bf[j] = *(const v8bf*)&Bsw[buf][q*1024 + (wn + j*16 + fr)*8];
            #pragma unroll
            for (int i = 0; i < 4; ++i)
                #pragma unroll
                for (int j = 0; j < 4; ++j)
                    acc[i][j] = __builtin_amdgcn_mfma_f32_16x16x32_bf16(af[i], bf[j], acc[i][j], 0, 0, 0);
            asm volatile("s_waitcnt vmcnt(0)" ::: "memory");
            __syncthreads();
            buf ^= 1;
        }
        // epilogue tile t: C/D layout col=lane&15, row=(lane>>4)*4+rr
        #pragma unroll
        for (int j = 0; j < 4; ++j) {
            int col = half*128 + wn + j*16 + fr;
            float bv_ = (j == 0) ? bc0 : (j == 1) ? bc1 : (j == 2) ? bc2 : bc3;
            #pragma unroll
            for (int rr = 0; rr < 4; ++rr) {
                long m = rowb + wm + q*4 + rr;
                long m1 = m + 16;  // i=1 handled below via loop
                (void)m1;
                #pragma unroll
                for (int i = 0; i < 4; ++i) {
                    long mi = rowb + wm + i*16 + q*4 + rr;
                    if (mi < MVAL) Cz[mi*256 + col] = f2b(acc[i][j][rr] + bv_);
                }
            }
        }
    }
}

// ---------------- fused softmax+locations (LDS) + vectorized bilinear gather ----
__global__ __launch_bounds__(256) void sample_fused(
    const u16* __restrict__ value, const float* __restrict__ offatt,
    const float* __restrict__ refp, const float* __restrict__ svr,
    u16* __restrict__ sampout)
{
    int row = blockIdx.x, t = threadIdx.x;
    int b = row / NQ, q = row % NQ;
    __shared__ float lg[128], awl[128], sxl[128], syl[128];
    const int WL[4] = {152,76,38,19}, HL[4] = {100,50,25,13}, LS[4] = {0,15200,19000,19950};

    if (t < 128) lg[t] = offatt[row*384 + 256 + t];
    __syncthreads();
    if (t < 128) {
        int h = t >> 4, s = t & 15, lvl = s >> 2, pp = s & 3;
        int gb = h << 4;
        float mx = -1e30f;
        for (int i = 0; i < 16; ++i) mx = fmaxf(mx, lg[gb + i]);
        float sm = 0.f;
        for (int i = 0; i < 16; ++i) sm += expf(lg[gb + i] - mx);
        awl[t] = expf(lg[t] - mx) / sm;
        float rx = refp[(b*350+q)*4 + 0] * svr[(b*4+lvl)*2 + 0];
        float ry = refp[(b*350+q)*4 + 1] * svr[(b*4+lvl)*2 + 1];
        float rw = refp[(b*350+q)*4 + 2] * svr[(b*4+lvl)*2 + 0];
        float rh = refp[(b*350+q)*4 + 3] * svr[(b*4+lvl)*2 + 1];
        float ox = offatt[row*384 + h*32 + lvl*8 + pp*2 + 0];
        float oy = offatt[row*384 + h*32 + lvl*8 + pp*2 + 1];
        sxl[t] = (rx + ox * 0.25f * rw * 0.5f) * (float)WL[lvl] - 0.5f;
        syl[t] = (ry + oy * 0.25f * rh * 0.5f) * (float)HL[lvl] - 0.5f;
    }
    __syncthreads();

    int lane = t & 63, wv = t >> 6;
    int g = lane >> 3, e = lane & 7;       // group handles one corner; lane -> 4 channels
    for (int hh = 0; hh < 2; ++hh) {
        int h = wv*2 + hh;
        float a0 = 0.f, a1 = 0.f, a2 = 0.f, a3 = 0.f;
        #pragma unroll
        for (int it = 0; it < 8; ++it) {
            int task = it*8 + g;           // 0..63 = s*4 + corner
            int s = task >> 2, cc = task & 3;
            int cx = cc & 1, cy = cc >> 1;
            int lvl = s >> 2;
            float x = sxl[h*16 + s], y2 = syl[h*16 + s], aw = awl[h*16 + s];
            float x0 = floorf(x), y0 = floorf(y2);
            float xc = x0 + (float)cx, yc = y0 + (float)cy;
            int wl = WL[lvl], hl = HL[lvl];
            if (xc >= 0.f && xc <= (float)(wl-1) && yc >= 0.f && yc <= (float)(hl-1)) {
                float lx = x - x0, ly = y2 - y0;
                float wgt = aw * (cx ? lx : 1.f - lx) * (cy ? ly : 1.f - ly);
                long off = ((long)b*S_TOTAL + LS[lvl] + (int)yc*wl + (int)xc)*256 + h*32 + e*4;
                uint2 v = *(const uint2*)(value + off);
                a0 += wgt * __uint_as_float((v.x & 0xffffu) << 16);
                a1 += wgt * __uint_as_float(v.x & 0xffff0000u);
                a2 += wgt * __uint_as_float((v.y & 0xffffu) << 16);
                a3 += wgt * __uint_as_float(v.y & 0xffff0000u);
            }
        }
        #pragma unroll
        for (int o = 8; o < 64; o <<= 1) {
            a0 += __shfl_xor(a0, o); a1 += __shfl_xor(a1, o);
            a2 += __shfl_xor(a2, o); a3 += __shfl_xor(a3, o);
        }
        if (g == 0)
            *(uint2*)&sampout[row*256 + h*32 + e*4] = make_uint2(pk2(a0, a1), pk2(a2, a3));
    }
}

// ---------------- residual + layernorm (writes f32 master + bf16 copy + q) -----
__global__ void ln_kernel(float* __restrict__ prop, const float* __restrict__ delta,
                          const float* __restrict__ w, const float* __restrict__ bsh,
                          u16* __restrict__ pb_out, u16* __restrict__ q_out,
                          const float* __restrict__ ppos)
{
    int row = blockIdx.x, t = threadIdx.x;
    int lane = t & 63, wv = t >> 6;
    float v = prop[row*256 + t] + delta[row*256 + t];
    float s = v;
    for (int o = 32; o; o >>= 1) s += __shfl_xor(s, o);
    __shared__ float red[4], red2[4];
    if (lane == 0) red[wv] = s;
    __syncthreads();
    float mean = (red[0]+red[1]+red[2]+red[3]) * (1.0f/256.0f);
    float dd = v - mean;
    float s2 = dd * dd;
    for (int o = 32; o; o >>= 1) s2 += __shfl_xor(s2, o);
    if (lane == 0) red2[wv] = s2;
    __syncthreads();
    float var = (red2[0]+red2[1]+red2[2]+red2[3]) * (1.0f/256.0f);
    float nv = dd * rsqrtf(var + 1e-5f) * w[t] + bsh[t];
    prop[row*256 + t] = nv;
    pb_out[row*256 + t] = f2b(nv);
    if (q_out) q_out[row*256 + t] = f2b(nv + ppos[row*256 + t]);
}

// ---------------- qk convert: f32 -> bf16 + per-head norms ---------------------
__global__ __launch_bounds__(128) void qk_convert(
    const float* __restrict__ qkp, const float* __restrict__ kt,
    u16* __restrict__ qk_b, u16* __restrict__ kt_b,
    float* __restrict__ qn_g, float* __restrict__ knp_g, float* __restrict__ knt_g)
{
    int row = blockIdx.x, t = threadIdx.x;
    __shared__ float part[128];
    if (row < ROWS) {
        const float* sp = qkp + (long)row*512 + t*4;
        float4 v = *(const float4*)sp;
        *(uint2*)&qk_b[(long)row*512 + t*4] = make_uint2(pk2(v.x,v.y), pk2(v.z,v.w));
        part[t] = v.x*v.x + v.y*v.y + v.z*v.z + v.w*v.w;
        __syncthreads();
        if (t < 4) {
            float s = 0.f;
            for (int i = 0; i < 32; ++i) s += part[t*32 + i];
            int b = row / NQ, q = row % NQ;
            float nv = sqrtf(s) + 1e-6f;
            if      (t == 0) qn_g [(b*2+0)*NQ + q] = nv;
            else if (t == 1) qn_g [(b*2+1)*NQ + q] = nv;
            else if (t == 2) knp_g[(b*2+0)*NQ + q] = nv;
            else             knp_g[(b*2+1)*NQ + q] = nv;
        }
    } else {
        int r2 = row - ROWS;                 // 0..399
        float ss = 0.f;
        if (t < 64) {
            const float* sp = kt + (long)r2*256 + t*4;
            float4 v = *(const float4*)sp;
            *(uint2*)&kt_b[(long)r2*256 + t*4] = make_uint2(pk2(v.x,v.y), pk2(v.z,v.w));
            ss = v.x*v.x + v.y*v.y + v.z*v.z + v.w*v.w;
        }
        part[t] = ss;
        __syncthreads();
        if (t < 2) {
            float s = 0.f;
            for (int i = 0; i < 32; ++i) s += part[t*32 + i];
            int b = r2 / NTQ, qq = r2 % NTQ;
            knt_g[(b*2+t)*NTQ + qq] = sqrtf(s) + 1e-6f;
        }
    }
}

// ---------------- weight_attn via MFMA: S=Q.K^T; cos + raw logits --------------
__global__ __launch_bounds__(256) void wattn_mfma(
    const u16* __restrict__ Qb, const u16* __restrict__ Kb,
    int qstride, int kstride, int koff, int nk,
    const float* __restrict__ qn_g, const float* __restrict__ kn_g,
    float* __restrict__ out_cos, float* __restrict__ out_logit)
{
    __shared__ __align__(16) u16 As[2][128*32];
    __shared__ __align__(16) u16 Bs[2][128*32];
    int bh = blockIdx.z, b = bh >> 1, h = bh & 1;
    int tid = threadIdx.x;
    int lane = tid & 63, wave = tid >> 6;
    int bm = blockIdx.y * 128, bn = blockIdx.x * 128;
    int wm = (wave >> 1) * 64, wn = (wave & 1) * 64;
    f32x4 acc[4][4] = {};
    int r = tid >> 2, c = (tid & 3) * 8;
    const u16* Ap0 = Qb + (long)(b*NQ + min(bm + r,      NQ-1))*qstride + h*128 + c;
    const u16* Ap1 = Qb + (long)(b*NQ + min(bm + r + 64, NQ-1))*qstride + h*128 + c;
    const u16* Bp0 = Kb + (long)(b*nk + min(bn + r,      nk-1))*kstride + koff + h*128 + c;
    const u16* Bp1 = Kb + (long)(b*nk + min(bn + r + 64, nk-1))*kstride + koff + h*128 + c;
    int fr = lane & 15, fk = (lane >> 4) * 8;

    auto STG = [&](int bi, int k0) {
        ASYNC_CP16(&As[bi][tid*8],         Ap0 + k0);
        ASYNC_CP16(&As[bi][64*32 + tid*8], Ap1 + k0);
        ASYNC_CP16(&Bs[bi][tid*8],         Bp0 + k0);
        ASYNC_CP16(&Bs[bi][64*32 + tid*8], Bp1 + k0);
    };
    STG(0, 0);
    asm volatile("s_waitcnt vmcnt(0)" ::: "memory");
    __syncthreads();
    int cur = 0;
    for (int k0 = 0; k0 < 128; k0 += 32) {
        if (k0 + 32 < 128) STG(cur ^ 1, k0 + 32);
        v8bf af[4], bf[4];
        #pragma unroll
        for (int i = 0; i < 4; ++i) af[i] = *(const v8bf*)&As[cur][(wm + i*16 + fr)*32 + fk];
        #pragma unroll
        for (int j = 0; j < 4; ++j) bf[j] = *(const v8bf*)&Bs[cur][(wn + j*16 + fr)*32 + fk];
        #pragma unroll
        for (int i = 0; i < 4; ++i)
            #pragma unroll
            for (int j = 0; j < 4; ++j)
                acc[i][j] = __builtin_amdgcn_mfma_f32_16x16x32_bf16(af[i], bf[j], acc[i][j], 0, 0, 0);
        asm volatile("s_waitcnt vmcnt(0)" ::: "memory");
        __syncthreads();
        cur ^= 1;
    }
    const float SC = 0.08838834764831845f;   // 1/sqrt(128)
    int cq = lane >> 4, cn = lane & 15;
    #pragma unroll
    for (int i = 0; i < 4; ++i) {
        #pragma unroll
        for (int j = 0; j < 4; ++j) {
            int col = bn + wn + j*16 + cn;
            #pragma unroll
            for (int rr = 0; rr < 4; ++rr) {
                int m = bm + wm + i*16 + cq*4 + rr;
                if (m < NQ && col < nk) {
                    float d = acc[i][j][rr];
                    long o = ((long)(bh*NQ + m))*nk + col;
                    out_cos[o]   = d / (qn_g[bh*NQ + m] * kn_g[bh*nk + col]);
                    out_logit[o] = d * SC;
                }
            }
        }
    }
}

// ---------------- in-place row softmax over nk ---------------------------------
__global__ __launch_bounds__(64) void row_softmax(float* __restrict__ buf, int nk)
{
    long row = blockIdx.x;
    float* p = buf + row*nk;
    int lane = threadIdx.x;
    float mx = -1e30f;
    for (int k = lane; k < nk; k += 64) mx = fmaxf(mx, p[k]);
    for (int o = 32; o; o >>= 1) mx = fmaxf(mx, __shfl_xor(mx, o));
    float s = 0.f;
    for (int k = lane; k < nk; k += 64) s += expf(p[k] - mx);
    for (int o = 32; o; o >>= 1) s += __shfl_xor(s, o);
    float inv = 1.0f / s;
    for (int k = lane; k < nk; k += 64) p[k] = expf(p[k] - mx) * inv;
}

__global__ void writeout_kernel(const float* __restrict__ prop, float* __restrict__ out)
{
    int row = blockIdx.x, t = threadIdx.x;
    out[row*256 + t] = prop[row*256 + t];
}

// ---------------- host launcher ----------------
extern "C" void kernel_launch(void* const* d_in, const int* in_sizes, int n_in,
                              void* d_out, int out_size, void* d_ws, size_t ws_size,
                              hipStream_t stream)
{
    (void)in_sizes; (void)n_in; (void)out_size; (void)ws_size;
    const float* tgt  = (const float*)d_in[0];
    const float* refp = (const float*)d_in[1];
    const float* src  = (const float*)d_in[2];
    const float* svr  = (const float*)d_in[5];
    const float* Woff = (const float*)d_in[7];
    const float* boff = (const float*)d_in[8];
    const float* Wa   = (const float*)d_in[9];
    const float* ba   = (const float*)d_in[10];
    const float* Wv   = (const float*)d_in[11];
    const float* bv   = (const float*)d_in[12];
    const float* Wout = (const float*)d_in[13];
    const float* bout = (const float*)d_in[14];
    const float* Wl1  = (const float*)d_in[15];
    const float* bl1  = (const float*)d_in[16];
    const float* Wl2  = (const float*)d_in[17];
    const float* bl2  = (const float*)d_in[18];
    const float* Wq   = (const float*)d_in[19];
    const float* bq   = (const float*)d_in[20];
    const float* Wk   = (const float*)d_in[21];
    const float* bk   = (const float*)d_in[22];
    const float* n1w  = (const float*)d_in[23];
    const float* n1b  = (const float*)d_in[24];
    const float* n3w  = (const float*)d_in[25];
    const float* n3b  = (const float*)d_in[26];
    float* out = (float*)d_out;

    char* p = (char*)d_ws;
    auto alloc = [&](size_t bytes) { void* r = (void*)p; p += (bytes + 255) & ~(size_t)255; return r; };
    u16*   wt      = (u16*)  alloc(6ull*884736*2);       // 10.6 MB
    float* bias    = (float*)alloc(6ull*2688*4);
    u16*   value   = (u16*)  alloc(6ull*MVAL*256*2);     // 496 MB (all 6 layers)
    u16*   src_b   = (u16*)  alloc((size_t)MVAL*256*2);  // 82.7 MB
    float* prop    = (float*)alloc((size_t)ROWS*256*4);
    u16*   prop_b  = (u16*)  alloc((size_t)ROWS*256*2);
    u16*   q_b     = (u16*)  alloc((size_t)ROWS*256*2);
    float* ppos    = (float*)alloc((size_t)ROWS*256*4);
    float* offatt  = (float*)alloc((size_t)ROWS*384*4);
    u16*   sampout = (u16*)  alloc((size_t)ROWS*256*2);
    float* ca      = (float*)alloc((size_t)ROWS*256*4);
    u16*   ff1     = (u16*)  alloc((size_t)ROWS*1024*2);
    float* ff2     = (float*)alloc((size_t)ROWS*256*4);
    u16*   tq      = (u16*)  alloc(400ull*256*2);
    float* qkp     = (float*)alloc((size_t)ROWS*512*4);
    float* kt      = (float*)alloc(400ull*256*4);
    u16*   qk_b    = (u16*)  alloc((size_t)ROWS*512*2);
    u16*   kt_b    = (u16*)  alloc(400ull*256*2);
    float* qn_g    = (float*)alloc(16ull*NQ*4);
    float* knp_g   = (float*)alloc(16ull*NQ*4);
    float* knt_g   = (float*)alloc(16ull*NTQ*4);

    transpose_pack<<<20799, 256, 0, stream>>>(Woff, Wa, Wv, Wout, Wl1, Wl2, Wq, Wk,
                                              boff, ba, bv, bout, bl1, bl2, bq, bk, wt, bias);
    src_convert<<<20197, 256, 0, stream>>>(src, src_b);
    setup_kernel<<<ROWS + 400, 256, 0, stream>>>(tgt, refp, prop, q_b, ppos, tq, out + 614400);
    // all 6 layers' value projections: A-stationary, A read from HBM once
    gemm_value6_v3<<<1263, 256, 0, stream>>>(src_b, wt, bias, value);

    for (int l = 0; l < NLAY; ++l) {
        const u16* wl_ = wt + (size_t)l*884736;
        const float* bl_ = bias + l*2688;
        gemm_bt64<<<dim3(3, 38), 256, 0, stream>>>(q_b,    wl_,          bl_,        offatt, ROWS, 384, 256, 0);
        sample_fused<<<ROWS, 256, 0, stream>>>(value + (size_t)l*MVAL*256, offatt, refp, svr, sampout);
        gemm_bt64<<<dim3(2, 38), 256, 0, stream>>>(sampout, wl_ + 163840, bl_ + 640,  ca,    ROWS, 256, 256, 0);
        ln_kernel<<<ROWS, 256, 0, stream>>>(prop, ca, n1w + l*256, n1b + l*256, prop_b, (u16*)nullptr, ppos);
        gemm_bt64<<<dim3(8, 38), 256, 0, stream>>>(prop_b, wl_ + 229376, bl_ + 896,  ff1,   ROWS, 1024, 256, 3);
        gemm_bt64<<<dim3(2, 38), 256, 0, stream>>>(ff1,    wl_ + 491520, bl_ + 1920, ff2,   ROWS, 256, 1024, 0);
        ln_kernel<<<ROWS, 256, 0, stream>>>(prop, ff2, n3w + l*256, n3b + l*256, prop_b, q_b, ppos);
    }

    const u16* w5 = wt + 5ull*884736;
    const float* b5 = bias + 5*2688;
    gemm_bt64<<<dim3(4, 38), 256, 0, stream>>>(prop_b, w5 + 753664,         b5 + 2176,       qkp, ROWS, 512, 256, 0);
    gemm_bt64<<<dim3(2, 7),  256, 0, stream>>>(tq,     w5 + 753664 + 65536, b5 + 2176 + 256, kt,  400,  256, 256, 0);
    qk_convert<<<2800, 128, 0, stream>>>(qkp, kt, qk_b, kt_b, qn_g, knp_g, knt_g);
    // pt: K from track queries (kt_b, stride 256, koff 0, nk=50)
    wattn_mfma<<<dim3(1, 3, 16), 256, 0, stream>>>(qk_b, kt_b, 512, 256, 0,   NTQ, qn_g, knt_g,
                                                   out + 624000, out + 2304000);
    // pp: K from proposals (qk_b, stride 512, koff 256, nk=300)
    wattn_mfma<<<dim3(3, 3, 16), 256, 0, stream>>>(qk_b, qk_b, 512, 512, 256, NQ,  qn_g, knp_g,
                                                   out + 864000, out + 2544000);
    row_softmax<<<4800, 64, 0, stream>>>(out + 2304000, NTQ);
    row_softmax<<<4800, 64, 0, stream>>>(out + 2544000, NQ);
    writeout_kernel<<<ROWS, 256, 0, stream>>>(prop, out);
}